// Round 11
// baseline (267.256 us; speedup 1.0000x reference)
//
#include <hip/hip_runtime.h>
#include <stdint.h>

#define K_TAGS   32
#define START_IX 30
#define END_IX   31
#define WIN      16

typedef short short8 __attribute__((ext_vector_type(8)));   // bf16x8 frag (guide §3)
typedef float f32x4  __attribute__((ext_vector_type(4)));
typedef __bf16 bf16;

// value of x at lane l^32 (validated a=b pattern, R2..R10)
__device__ __forceinline__ float xswap32(float x, bool hi) {
    float a = x, b = x;
    asm volatile("v_permlane32_swap_b32 %0, %1" : "+v"(a), "+v"(b));
    return hi ? a : b;
}

__device__ __forceinline__ short bf16bits(float x) {
    union { bf16 b; short s; } u; u.b = (bf16)x; return u.s;
}

// MFMA CRF: state S[pos 0..31][col 0..15] bf16 in B-frag layout (lane l holds
// pos 8q+j, col l&15; q=l>>4). cols 0,1 = the block's 2 real batches (others
// mirror col&1 harmlessly). Step: P = A_m x S (2x mfma_f32_16x16x32_bf16, A_m
// = position-permuted exp(trans)^T constants), P *= g (pre-exp'd in LDS),
// renorm every 8 (exact pow2, off), cvt back to bf16 -> next S. The C/D->B
// layout permutation is folded into A: A_m[row][k] = Ehat[k][8*(row>>2)+4m+
// (row&3)], so P0.xyzw,P1.xyzw are exactly next-B elements j=0..7. No per-step
// cross-lane ops at all.
__global__
__attribute__((amdgpu_flat_work_group_size(64, 64), amdgpu_waves_per_eu(1, 1)))
void crf_fwd_kernel(
    const float* __restrict__ frames,   // [B][T][32]
    const float* __restrict__ trans,    // [32][32] prev->cur
    float* __restrict__ out,            // [B]
    int T)
{
    __shared__ float fbuf[2][2][WIN][K_TAGS];  // [buf][b][t][k] 2x4KB raw frames
    __shared__ float gbuf[WIN][2][K_TAGS];     // [t][b][k] 4KB pre-exp'd g

    const int  l   = threadIdx.x;
    const int  q   = l >> 4;
    const int  col = l & 15;
    const bool hi  = (l >= 32);
    const float L2E = 1.44269504088896340736f;

    // ---- constant A-frags: A_m elem j = Ehat[8q+j][kp + 4m] (bf16 bits) ----
    // trans[:,START]=-1e4 and trans[END,:]=-1e4 underflow to exactly 0.
    const int kp = 8 * (col >> 2) + (col & 3);
    short8 A0, A1;
#pragma unroll
    for (int j = 0; j < 8; ++j) {
        int k = 8 * q + j;
        A0[j] = bf16bits(exp2f(trans[k * 32 + kp]     * L2E));
        A1[j] = bf16bits(exp2f(trans[k * 32 + kp + 4] * L2E));
    }
    float Eend[8];
#pragma unroll
    for (int j = 0; j < 8; ++j)
        Eend[j] = exp2f(trans[(8 * q + j) * 32 + END_IX] * L2E);

    // ---- state init: alpha0 = e_START (pos 30 = 8*3+6 -> q==3, elem 6) ----
    short8 S;
#pragma unroll
    for (int j = 0; j < 8; ++j) S[j] = 0;
    if (q == 3) S[6] = bf16bits(1.0f);
    int off = 0;

    // ---- staging: instr k -> fbuf[buf][k>>1][(k&1)*8 + (l>>3)][(l&7)*4 ..+3]
    const float* sbase[4];
#pragma unroll
    for (int k = 0; k < 4; ++k)
        sbase[k] = frames
            + ((size_t)(blockIdx.x * 2 + (k >> 1)) * T + (k & 1) * 8 + (l >> 3)) * K_TAGS
            + (l & 7) * 4;

#pragma unroll
    for (int k = 0; k < 4; ++k)
        __builtin_amdgcn_global_load_lds(
            (const __attribute__((address_space(1))) unsigned int*)(sbase[k]),
            (__attribute__((address_space(3))) unsigned int*)((char*)&fbuf[0][0][0][0] + k * 1024),
            16, 0, 0);

    int buf = 0;
    for (int t0 = 0; t0 < T; t0 += WIN) {
        asm volatile("s_waitcnt vmcnt(0)" ::: "memory");
        __builtin_amdgcn_sched_barrier(0);

        // frames -> g (exp2(f*log2e - 6)): lane handles b=l>>5, t=(l>>1)&15,
        // kappa = (l&1)*16 .. +15  (16 contiguous floats in, 16 out)
        {
            const float* fr = (const float*)&fbuf[buf][0][0][0] + l * 16;
            float v[16];
#pragma unroll
            for (int i = 0; i < 16; ++i) v[i] = fr[i];
#pragma unroll
            for (int i = 0; i < 16; ++i) v[i] = exp2f(fmaf(v[i], L2E, -6.0f));
            float* gw = &gbuf[(l >> 1) & 15][l >> 5][(l & 1) * 16];
#pragma unroll
            for (int i = 0; i < 16; ++i) gw[i] = v[i];
        }

        {   // stage next window into the other buffer
            int tn = t0 + WIN; if (tn > T - WIN) tn = T - WIN;   // uniform clamp
            char* ldsn = (char*)&fbuf[buf ^ 1][0][0][0];
#pragma unroll
            for (int k = 0; k < 4; ++k)
                __builtin_amdgcn_global_load_lds(
                    (const __attribute__((address_space(1))) unsigned int*)(sbase[k] + (size_t)tn * K_TAGS),
                    (__attribute__((address_space(3))) unsigned int*)(ldsn + k * 1024),
                    16, 0, 0);
        }

        // g writes must land before step-loop reads (same wave, lgkm ordering)
        asm volatile("s_waitcnt lgkmcnt(0)" ::: "memory");
        __builtin_amdgcn_sched_barrier(0);

        // ---- 16 recurrence steps: 2 MFMA + 2 ds_read + 8 mul + 8 cvt ----
#pragma unroll
        for (int jj = 0; jj < WIN; ++jj) {
            const float* gp = &gbuf[jj][l & 1][8 * q];
            f32x4 gA = *(const f32x4*)gp;
            f32x4 gB = *(const f32x4*)(gp + 4);

            f32x4 z = {0.f, 0.f, 0.f, 0.f};
            f32x4 P0 = __builtin_amdgcn_mfma_f32_16x16x32_bf16(A0, S, z, 0, 0, 0);
            f32x4 P1 = __builtin_amdgcn_mfma_f32_16x16x32_bf16(A1, S, z, 0, 0, 0);
            P0 *= gA;
            P1 *= gB;

            if ((jj & 7) == 7) {
                // per-column exact pow2 renorm: max over the 4 lanes sharing col
                float m = fmaxf(fmaxf(fmaxf(P0.x, P0.y), fmaxf(P0.z, P0.w)),
                                fmaxf(fmaxf(P1.x, P1.y), fmaxf(P1.z, P1.w)));
                m = fmaxf(m, xswap32(m, hi));
                m = fmaxf(m, __shfl_xor(m, 16, 64));
                int e = (int)((__float_as_uint(m) >> 23) & 255u) - 127;
                float sc = __uint_as_float((uint32_t)(127 - e) << 23);
                P0 *= sc;
                P1 *= sc;
                off += e;
            }

            S[0] = bf16bits(P0.x); S[1] = bf16bits(P0.y);
            S[2] = bf16bits(P0.z); S[3] = bf16bits(P0.w);
            S[4] = bf16bits(P1.x); S[5] = bf16bits(P1.y);
            S[6] = bf16bits(P1.z); S[7] = bf16bits(P1.w);
        }
        buf ^= 1;
    }

    // ---- epilogue: Z_col = sum_pos S[pos][col] * exp(trans[pos][END]) ----
    float s = 0.f;
#pragma unroll
    for (int j = 0; j < 8; ++j) {
        union { short sh; bf16 b; } u; u.sh = S[j];
        s = fmaf((float)u.b, Eend[j], s);
    }
    s += xswap32(s, hi);
    s += __shfl_xor(s, 16, 64);

    if (l < 2) {   // lanes 0,1: col 0,1 at q=0
        double res = ((double)(off + 6 * T) + (double)log2f(s)) * 0.693147180559945309417;
        out[blockIdx.x * 2 + l] = (float)res;
    }
}

extern "C" void kernel_launch(void* const* d_in, const int* in_sizes, int n_in,
                              void* d_out, int out_size, void* d_ws, size_t ws_size,
                              hipStream_t stream)
{
    const float* frames = (const float*)d_in[0];
    const float* trans  = (const float*)d_in[1];
    float* out = (float*)d_out;

    const int B = out_size;                     // 1024
    const int T = in_sizes[0] / (B * K_TAGS);   // 1024 (multiple of WIN)

    dim3 grid(B / 2), block(64);
    crf_fwd_kernel<<<grid, block, 0, stream>>>(frames, trans, out, T);
}